// Round 10
// baseline (12257.899 us; speedup 1.0000x reference)
//
#include <hip/hip_runtime.h>
#include <hip/hip_fp16.h>
#include <cstdint>

#define B_SZ 4
#define T_SZ 512
#define D_SZ 768
#define H_SZ 768
#define G4   3072           // 4*H
#define V_SZ 50257
#define V_PAD 50304         // 393*128
#define M_SZ 2048           // T*B
#define FUSE_WGS 96         // one block = 8 cols of L0 (waves 0-3) + 8 cols of L1 (waves 4-7)

using half8 = __attribute__((ext_vector_type(8))) _Float16;
using f32x4 = __attribute__((ext_vector_type(4))) float;
typedef unsigned long long ull;

// ---------------- conversion kernels ----------------

__global__ void conv_A0(const float* __restrict__ reps, _Float16* __restrict__ A0) {
  // A0[(t*4+b)*768 + k] = reps[(b*512 + t)*768 + k]
  int idx = blockIdx.x * blockDim.x + threadIdx.x;
  const int total = M_SZ * D_SZ;
  for (; idx < total; idx += gridDim.x * blockDim.x) {
    int k = idx % D_SZ, m = idx / D_SZ;
    int t = m >> 2, b = m & 3;
    A0[idx] = (_Float16)reps[(b * T_SZ + t) * D_SZ + k];
  }
}

__global__ void conv_cast(const float* __restrict__ src, _Float16* __restrict__ dst, int n) {
  int idx = blockIdx.x * blockDim.x + threadIdx.x;
  for (; idx < n; idx += gridDim.x * blockDim.x) dst[idx] = (_Float16)src[idx];
}

__global__ void conv_head(const float* __restrict__ w, _Float16* __restrict__ dst) {
  int idx = blockIdx.x * blockDim.x + threadIdx.x;
  const int total = V_PAD * H_SZ;
  for (; idx < total; idx += gridDim.x * blockDim.x) {
    int n = idx / H_SZ, k = idx % H_SZ;
    dst[idx] = (n < V_SZ) ? (_Float16)w[n * H_SZ + k] : (_Float16)0.f;
  }
}

// ---------------- f16 MFMA GEMM: C[m][n] = sum_k A[m][k]*B[n][k] + bias[n] ----------------

__global__ __launch_bounds__(256) void gemm_bt_f16(
    const _Float16* __restrict__ A, const _Float16* __restrict__ B,
    const float* __restrict__ bias, float* __restrict__ C,
    int M, int N, int K, int mode, int Nreal)
{
  __shared__ __align__(16) _Float16 As[128][32];
  __shared__ __align__(16) _Float16 Bs[128][32];
  const int t = threadIdx.x;
  const int lane = t & 63, w = t >> 6;
  const int wr = w >> 1, wc = w & 1;
  const int m0 = blockIdx.x * 128, n0 = blockIdx.y * 128;

  f32x4 acc[4][4] = {};

  const int srow = t >> 2;
  const int scol = (t & 3) * 8;

  for (int k0 = 0; k0 < K; k0 += 32) {
    uint4 av0 = *(const uint4*)&A[(size_t)(m0 + srow) * K + k0 + scol];
    uint4 av1 = *(const uint4*)&A[(size_t)(m0 + 64 + srow) * K + k0 + scol];
    uint4 bv0 = *(const uint4*)&B[(size_t)(n0 + srow) * K + k0 + scol];
    uint4 bv1 = *(const uint4*)&B[(size_t)(n0 + 64 + srow) * K + k0 + scol];
    __syncthreads();
    *(uint4*)&As[srow][scol]      = av0;
    *(uint4*)&As[64 + srow][scol] = av1;
    *(uint4*)&Bs[srow][scol]      = bv0;
    *(uint4*)&Bs[64 + srow][scol] = bv1;
    __syncthreads();

    const int fr = lane & 15, k8 = (lane >> 4) * 8;
    half8 af[4], bf[4];
#pragma unroll
    for (int i = 0; i < 4; ++i) {
      af[i] = *(const half8*)&As[wr * 64 + i * 16 + fr][k8];
      bf[i] = *(const half8*)&Bs[wc * 64 + i * 16 + fr][k8];
    }
#pragma unroll
    for (int i = 0; i < 4; ++i)
#pragma unroll
      for (int j = 0; j < 4; ++j)
        acc[i][j] = __builtin_amdgcn_mfma_f32_16x16x32_f16(af[i], bf[j], acc[i][j], 0, 0, 0);
  }

  const int fr = lane & 15, rq = lane >> 4;
#pragma unroll
  for (int i = 0; i < 4; ++i) {
#pragma unroll
    for (int j = 0; j < 4; ++j) {
      int n = n0 + wc * 64 + j * 16 + fr;
      if (n >= Nreal) continue;
      float bv = bias[n];
#pragma unroll
      for (int r = 0; r < 4; ++r) {
        int m = m0 + wr * 64 + i * 16 + rq * 4 + r;
        float v = acc[i][j][r] + bv;
        if (mode == 0) {
          C[(size_t)m * N + n] = v;
        } else {
          int tt = m >> 2, bb = m & 3;
          C[(size_t)(bb * T_SZ + tt) * V_SZ + n] = v;
        }
      }
    }
  }
}

// ---------------- fused 2-layer pipelined LSTM scan: 96 blocks x 512 threads ----------------
// Block owns h-cols [j0, j0+8) of BOTH layers. Waves 0-3: L0 gates; waves 4-7: L1 gates.
// Epoch e (0..512): L0 computes step e (e<512) from h0buf=H0[e-1]; L1 computes step e-1
// (e>=1) from x=H0[e-1], carry H1[e-2]. xg1 = in-register matvec (wreg2).
// Sync (round-6-proven): relaxed agent-scope flags, 96 lines, one per block.
// Wave 0 performs BOTH layers' gate-combine and owns ALL global h-stores ->
// single inline s_waitcnt vmcnt(0) then one flag store (= e+2) at the tail.
// Poll at e>=1: t<96 wait flags >= e+1. Parity: read hx[e&1], write hx[(e+1)&1].
// Flags monotone; hx0/hx1/flags memset 0 before launch.
//
// __launch_bounds__(512, 1): VGPR budget history --
//   round 8: (512)    -> compiler targeted 4 waves/EU -> 128 VGPR -> weight
//            spills -> 6 GB scratch refetch/launch (FETCH_SIZE), 23 us/epoch.
//   round 9: (512, 2) -> STILL 128 VGPR (hipcc second arg behaves as CUDA
//            min-blocks: 2 blocks x 8 waves / 4 EU = 4 waves/EU -> 128 cap).
//   now:     (512, 1) -> 1 block x 8 waves / 4 EU = 2 waves/EU -> 256 VGPR
//            budget under either attribute interpretation. Weights resident.

__global__ __launch_bounds__(512, 1) void lstm_fused(
    const float* __restrict__ xg0,    // (2048,3072) layer-0 input projections
    const float* __restrict__ Wih1,   // (3072,768) fp32 layer-1 input weights
    const float* __restrict__ Whh,    // (2,3072,768) fp32
    const float* __restrict__ bias,   // (2,3072) fp32
    float* __restrict__ hx0,          // [2][3072] (k,b), pre-zeroed
    float* __restrict__ hx1,          // [2][3072] (k,b), pre-zeroed
    _Float16* __restrict__ h1hist,    // (2048,768) fp16, row = t*4+b
    unsigned* __restrict__ flags)     // [96*32], pre-zeroed
{
  __shared__ __align__(16) float h0buf[H_SZ * 4];   // [k][b]
  __shared__ __align__(16) float h1buf[H_SZ * 4];   // [k][b]
  __shared__ __align__(16) float redA[4][8][4][4];  // L0 [gate][c][q][b]
  __shared__ __align__(16) float redB[4][8][4][4];  // L1
  __shared__ float actvA[4][8][4], actvB[4][8][4];
  __shared__ float cst0[8][4], cst1[8][4];

  const int t = threadIdx.x, lane = t & 63, wv = t >> 6;
  const int j0 = blockIdx.x * 8;
  const bool isL1w = wv >= 4;
  const int g = isL1w ? (wv - 4) : wv;   // gate index within layer

  // W_hh slice in registers (layer per wave group)
  const float* WhhL = Whh + (isL1w ? (size_t)G4 * H_SZ : 0);
  float wreg[8][12];
#pragma unroll
  for (int c = 0; c < 8; ++c)
#pragma unroll
    for (int kk = 0; kk < 12; ++kk)
      wreg[c][kk] = WhhL[(size_t)(g * H_SZ + j0 + c) * H_SZ + kk * 64 + lane];

  // L1 waves also hold W_ih1 slice
  float wreg2[8][12];
  if (isL1w) {
#pragma unroll
    for (int c = 0; c < 8; ++c)
#pragma unroll
      for (int kk = 0; kk < 12; ++kk)
        wreg2[c][kk] = Wih1[(size_t)(g * H_SZ + j0 + c) * H_SZ + kk * 64 + lane];
  }

  float breg = 0.f;
  if (t >= 256 && t < 384) {
    int t2 = t - 256;
    breg = bias[G4 + (t2 >> 5) * H_SZ + j0 + ((t2 >> 2) & 7)];
  }

  if (t < 32) cst0[t >> 2][t & 3] = 0.f;
  else if (t < 64) cst1[(t - 32) >> 2][(t - 32) & 3] = 0.f;

  for (int e = 0; e <= 512; ++e) {
    // L0 xg prefetch (independent of h) before the poll
    float xgv = 0.f;
    if (t < 128 && e < 512)
      xgv = xg0[(size_t)((e << 2) + (t & 3)) * G4 + (t >> 5) * H_SZ + j0 + ((t >> 2) & 7)];

    if (e >= 1 && t < FUSE_WGS) {
      while (__hip_atomic_load(&flags[t * 32], __ATOMIC_RELAXED, __HIP_MEMORY_SCOPE_AGENT)
             < (unsigned)(e + 1))
        __builtin_amdgcn_s_sleep(1);
    }
    __syncthreads();

    // gather both h states (parity e&1) into LDS: 3 x 8B slots each per thread
    {
      const ull* s0 = (const ull*)(hx0 + ((e & 1) ? 3072 : 0));
      const ull* s1 = (const ull*)(hx1 + ((e & 1) ? 3072 : 0));
      ull* d0 = (ull*)h0buf;
      ull* d1 = (ull*)h1buf;
#pragma unroll
      for (int i = 0; i < 3; ++i)
        d0[t + i * 512] = __hip_atomic_load(&s0[t + i * 512], __ATOMIC_RELAXED, __HIP_MEMORY_SCOPE_AGENT);
#pragma unroll
      for (int i = 0; i < 3; ++i)
        d1[t + i * 512] = __hip_atomic_load(&s1[t + i * 512], __ATOMIC_RELAXED, __HIP_MEMORY_SCOPE_AGENT);
    }
    __syncthreads();

    // matvec + butterfly reduce (wave-uniform guards)
    const bool act = isL1w ? (e >= 1) : (e < 512);
    if (act) {
      float4 acc[8];
#pragma unroll
      for (int c = 0; c < 8; ++c) acc[c] = make_float4(0.f, 0.f, 0.f, 0.f);

      if (!isL1w) {
#pragma unroll
        for (int kk = 0; kk < 12; ++kk) {
          float4 h4 = *(const float4*)&h0buf[(kk * 64 + lane) * 4];
#pragma unroll
          for (int c = 0; c < 8; ++c) {
            float wf = wreg[c][kk];
            acc[c].x = fmaf(wf, h4.x, acc[c].x);
            acc[c].y = fmaf(wf, h4.y, acc[c].y);
            acc[c].z = fmaf(wf, h4.z, acc[c].z);
            acc[c].w = fmaf(wf, h4.w, acc[c].w);
          }
        }
      } else {
#pragma unroll
        for (int kk = 0; kk < 12; ++kk) {
          float4 x4 = *(const float4*)&h0buf[(kk * 64 + lane) * 4];  // x = H0[e-1]
          float4 h4 = *(const float4*)&h1buf[(kk * 64 + lane) * 4];  // carry H1[e-2]
#pragma unroll
          for (int c = 0; c < 8; ++c) {
            float wx = wreg2[c][kk], wh = wreg[c][kk];
            acc[c].x = fmaf(wx, x4.x, fmaf(wh, h4.x, acc[c].x));
            acc[c].y = fmaf(wx, x4.y, fmaf(wh, h4.y, acc[c].y));
            acc[c].z = fmaf(wx, x4.z, fmaf(wh, h4.z, acc[c].z));
            acc[c].w = fmaf(wx, x4.w, fmaf(wh, h4.w, acc[c].w));
          }
        }
      }

#pragma unroll
      for (int mask = 1; mask <= 8; mask <<= 1) {
#pragma unroll
        for (int c = 0; c < 8; ++c) {
          acc[c].x += __shfl_xor(acc[c].x, mask, 64);
          acc[c].y += __shfl_xor(acc[c].y, mask, 64);
          acc[c].z += __shfl_xor(acc[c].z, mask, 64);
          acc[c].w += __shfl_xor(acc[c].w, mask, 64);
        }
      }
      if ((lane & 15) == 0) {
        int q = lane >> 4;
        float (*red)[8][4][4] = isL1w ? redB : redA;
#pragma unroll
        for (int c = 0; c < 8; ++c) *(float4*)&red[g][c][q][0] = acc[c];
      }
    }
    __syncthreads();

    // activations
    if (t < 128 && e < 512) {
      int gg = t >> 5, c = (t >> 2) & 7, b = t & 3;
      float s = redA[gg][c][0][b] + redA[gg][c][1][b] + redA[gg][c][2][b] + redA[gg][c][3][b] + xgv;
      actvA[gg][c][b] = (gg == 2) ? tanhf(s) : (1.f / (1.f + expf(-s)));
    } else if (t >= 256 && t < 384 && e >= 1) {
      int t2 = t - 256;
      int gg = t2 >> 5, c = (t2 >> 2) & 7, b = t2 & 3;
      float s = redB[gg][c][0][b] + redB[gg][c][1][b] + redB[gg][c][2][b] + redB[gg][c][3][b] + breg;
      actvB[gg][c][b] = (gg == 2) ? tanhf(s) : (1.f / (1.f + expf(-s)));
    }
    __syncthreads();

    // combine + ALL global h stores in wave 0
    if (t < 32) {
      if (e < 512) {
        int c = t >> 2, b = t & 3;
        float iv = actvA[0][c][b], fv = actvA[1][c][b], gv = actvA[2][c][b], ov = actvA[3][c][b];
        float cn = fv * cst0[c][b] + iv * gv;
        cst0[c][b] = cn;
        float hn = ov * tanhf(cn);
        float* hnext = hx0 + (((e + 1) & 1) ? 3072 : 0);
        __hip_atomic_store(&hnext[(j0 + c) * 4 + b], hn,
                           __ATOMIC_RELAXED, __HIP_MEMORY_SCOPE_AGENT);
      }
    } else if (t < 64) {
      if (e >= 1) {
        int u = t - 32, c = u >> 2, b = u & 3;
        float iv = actvB[0][c][b], fv = actvB[1][c][b], gv = actvB[2][c][b], ov = actvB[3][c][b];
        float cn = fv * cst1[c][b] + iv * gv;
        cst1[c][b] = cn;
        float hn = ov * tanhf(cn);
        float* hnext = hx1 + (((e + 1) & 1) ? 3072 : 0);
        __hip_atomic_store(&hnext[(j0 + c) * 4 + b], hn,
                           __ATOMIC_RELAXED, __HIP_MEMORY_SCOPE_AGENT);
        h1hist[(size_t)(((e - 1) << 2) + b) * H_SZ + j0 + c] = (_Float16)hn;
      }
    }

    // tail publication: wave 0 owns all h-stores; drain then flag
    if (e < 512 && wv == 0) {
      asm volatile("s_waitcnt vmcnt(0)" ::: "memory");
      if (t == 0)
        __hip_atomic_store(&flags[blockIdx.x * 32], (unsigned)(e + 2),
                           __ATOMIC_RELAXED, __HIP_MEMORY_SCOPE_AGENT);
    }
    // top-of-epoch poll + __syncthreads separate this epoch's LDS/global
    // reads from next epoch's overwrites (see round-6 safety argument).
  }
}

// ---------------- launcher ----------------

extern "C" void kernel_launch(void* const* d_in, const int* in_sizes, int n_in,
                              void* d_out, int out_size, void* d_ws, size_t ws_size,
                              hipStream_t stream) {
  const float* reps   = (const float*)d_in[0];
  const float* W_ih   = (const float*)d_in[1];
  const float* W_hh   = (const float*)d_in[2];
  const float* bias   = (const float*)d_in[3];
  const float* head_w = (const float*)d_in[4];
  const float* head_b = (const float*)d_in[5];
  float* out = (float*)d_out;

  char* ws = (char*)d_ws;
  _Float16* A0h    = (_Float16*)(ws + 0);            //  3,145,728 B
  _Float16* Wih_h  = (_Float16*)(ws + 3145728);      //  4,718,592 B (layer 0 only)
  _Float16* Whead  = (_Float16*)(ws + 12582912);     // 77,266,944 B (padded)
  float*    xg0    = (float*)   (ws + 89849856);     // 25,165,824 B
  _Float16* h1hist = (_Float16*)(ws + 115015680);    //  3,145,728 B
  float*    hx0    = (float*)   (ws + 118161408);    //     24,576 B
  float*    hx1    = (float*)   (ws + 118185984);    //     24,576 B
  unsigned* flags  = (unsigned*)(ws + 118210560);    //     12,288 B (96*128B)

  // conversions
  hipLaunchKernelGGL(conv_A0,   dim3(1024), dim3(256), 0, stream, reps, A0h);
  hipLaunchKernelGGL(conv_cast, dim3(1024), dim3(256), 0, stream, W_ih, Wih_h, G4 * D_SZ);
  hipLaunchKernelGGL(conv_head, dim3(4096), dim3(256), 0, stream, head_w, Whead);

  // xg0 = A0 * Wih0^T + b0
  hipLaunchKernelGGL(gemm_bt_f16, dim3(16, 24), dim3(256), 0, stream,
                     A0h, Wih_h, bias, xg0, M_SZ, G4, H_SZ, 0, G4);

  // fused pipelined 2-layer scan (96 blocks x 512 threads, co-resident)
  hipMemsetAsync(hx0, 0, 61440, stream);  // hx0 + hx1 + flags contiguous
  hipLaunchKernelGGL(lstm_fused, dim3(FUSE_WGS), dim3(512), 0, stream,
                     xg0, W_ih + (size_t)G4 * D_SZ, W_hh, bias,
                     hx0, hx1, h1hist, flags);

  // logits = h1 * head_w^T + head_b  (padded N, permuted store into (B,T,V))
  hipLaunchKernelGGL(gemm_bt_f16, dim3(16, 393), dim3(256), 0, stream,
                     h1hist, Whead, head_b, out, M_SZ, V_PAD, H_SZ, 1, V_SZ);
}

// Round 11
// 4120.985 us; speedup vs baseline: 2.9745x; 2.9745x over previous
//
#include <hip/hip_runtime.h>
#include <hip/hip_fp16.h>
#include <cstdint>

#define B_SZ 4
#define T_SZ 512
#define D_SZ 768
#define H_SZ 768
#define G4   3072           // 4*H
#define V_SZ 50257
#define V_PAD 50304         // 393*128
#define M_SZ 2048           // T*B
#define FUSE_WGS 192        // 96 L0 blocks + 96 L1 blocks, 256 threads each

using half8 = __attribute__((ext_vector_type(8))) _Float16;
using f32x4 = __attribute__((ext_vector_type(4))) float;
typedef unsigned long long ull;

// ---------------- conversion kernels ----------------

__global__ void conv_A0(const float* __restrict__ reps, _Float16* __restrict__ A0) {
  // A0[(t*4+b)*768 + k] = reps[(b*512 + t)*768 + k]
  int idx = blockIdx.x * blockDim.x + threadIdx.x;
  const int total = M_SZ * D_SZ;
  for (; idx < total; idx += gridDim.x * blockDim.x) {
    int k = idx % D_SZ, m = idx / D_SZ;
    int t = m >> 2, b = m & 3;
    A0[idx] = (_Float16)reps[(b * T_SZ + t) * D_SZ + k];
  }
}

__global__ void conv_cast(const float* __restrict__ src, _Float16* __restrict__ dst, int n) {
  int idx = blockIdx.x * blockDim.x + threadIdx.x;
  for (; idx < n; idx += gridDim.x * blockDim.x) dst[idx] = (_Float16)src[idx];
}

__global__ void conv_head(const float* __restrict__ w, _Float16* __restrict__ dst) {
  int idx = blockIdx.x * blockDim.x + threadIdx.x;
  const int total = V_PAD * H_SZ;
  for (; idx < total; idx += gridDim.x * blockDim.x) {
    int n = idx / H_SZ, k = idx % H_SZ;
    dst[idx] = (n < V_SZ) ? (_Float16)w[n * H_SZ + k] : (_Float16)0.f;
  }
}

// ---------------- f16 MFMA GEMM: C[m][n] = sum_k A[m][k]*B[n][k] + bias[n] ----------------

__global__ __launch_bounds__(256) void gemm_bt_f16(
    const _Float16* __restrict__ A, const _Float16* __restrict__ B,
    const float* __restrict__ bias, float* __restrict__ C,
    int M, int N, int K, int mode, int Nreal)
{
  __shared__ __align__(16) _Float16 As[128][32];
  __shared__ __align__(16) _Float16 Bs[128][32];
  const int t = threadIdx.x;
  const int lane = t & 63, w = t >> 6;
  const int wr = w >> 1, wc = w & 1;
  const int m0 = blockIdx.x * 128, n0 = blockIdx.y * 128;

  f32x4 acc[4][4] = {};

  const int srow = t >> 2;
  const int scol = (t & 3) * 8;

  for (int k0 = 0; k0 < K; k0 += 32) {
    uint4 av0 = *(const uint4*)&A[(size_t)(m0 + srow) * K + k0 + scol];
    uint4 av1 = *(const uint4*)&A[(size_t)(m0 + 64 + srow) * K + k0 + scol];
    uint4 bv0 = *(const uint4*)&B[(size_t)(n0 + srow) * K + k0 + scol];
    uint4 bv1 = *(const uint4*)&B[(size_t)(n0 + 64 + srow) * K + k0 + scol];
    __syncthreads();
    *(uint4*)&As[srow][scol]      = av0;
    *(uint4*)&As[64 + srow][scol] = av1;
    *(uint4*)&Bs[srow][scol]      = bv0;
    *(uint4*)&Bs[64 + srow][scol] = bv1;
    __syncthreads();

    const int fr = lane & 15, k8 = (lane >> 4) * 8;
    half8 af[4], bf[4];
#pragma unroll
    for (int i = 0; i < 4; ++i) {
      af[i] = *(const half8*)&As[wr * 64 + i * 16 + fr][k8];
      bf[i] = *(const half8*)&Bs[wc * 64 + i * 16 + fr][k8];
    }
#pragma unroll
    for (int i = 0; i < 4; ++i)
#pragma unroll
      for (int j = 0; j < 4; ++j)
        acc[i][j] = __builtin_amdgcn_mfma_f32_16x16x32_f16(af[i], bf[j], acc[i][j], 0, 0, 0);
  }

  const int fr = lane & 15, rq = lane >> 4;
#pragma unroll
  for (int i = 0; i < 4; ++i) {
#pragma unroll
    for (int j = 0; j < 4; ++j) {
      int n = n0 + wc * 64 + j * 16 + fr;
      if (n >= Nreal) continue;
      float bv = bias[n];
#pragma unroll
      for (int r = 0; r < 4; ++r) {
        int m = m0 + wr * 64 + i * 16 + rq * 4 + r;
        float v = acc[i][j][r] + bv;
        if (mode == 0) {
          C[(size_t)m * N + n] = v;
        } else {
          int tt = m >> 2, bb = m & 3;
          C[(size_t)(bb * T_SZ + tt) * V_SZ + n] = v;
        }
      }
    }
  }
}

// ---------------- decoupled 2-group pipelined LSTM scan: 192 blocks x 256 threads ----------------
// Blocks 0..95 = L0 (8 h0-cols each); 96..191 = L1 (8 h1-cols each, lag-1).
// h0 lives in a DEPTH-4 ring: slot t&3 holds h0[t] (slot 3 pre-zeroed = h0[-1]).
// h1 lives in a parity double buffer (as round 7).
// Epoch e: L0 (e=0..511) computes h0[e] from h0[e-1]; L1 (e=0..512, act at e>=1)
// computes h1[e-1] from x=h0[e-1] (ring) + carry h1[e-2] (parity e&1).
// Flags: 192 x 128B lines; block publishes flags[gid*32] = e+2 after epoch e
// (wave 0 owns all h-state stores; inline s_waitcnt vmcnt(0) then flag store).
// DECOUPLED polls (the round-11 change):
//   L0 at e>=1:  t<96   : flags0 >= e+1  (own group: h0[e-1] complete)
//                t in [96,192): flags1 >= e-1  (L1 consumed h0[e-4]; slack 2)
//   L1 at e>=1:  t<96   : flags0 >= e+1  (h0[e-1] ready; pre-satisfied, L0 ahead)
//                t in [96,192): flags1 >= e+1  (own group: h1 parity safety)
// So L0 free-runs up to 2 epochs ahead; L1's cadence = its own path only.
// h1hist store deferred until AFTER the flag publish (no in-kernel consumers).
// Deadlock-free: L0->L1 dependence lagged by 2; L1->L0 satisfied by L0's lead.
// 256-thread blocks: compiler grants ~244 VGPR (rounds 8-10: 512-thread blocks
// stuck at 128 VGPR regardless of __launch_bounds__ -> weight spills, 6 GB).

__global__ __launch_bounds__(256) void lstm_fused(
    const float* __restrict__ xg0,    // (2048,3072) layer-0 input projections
    const float* __restrict__ Wih1,   // (3072,768) fp32 layer-1 input weights
    const float* __restrict__ Whh,    // (2,3072,768) fp32
    const float* __restrict__ bias,   // (2,3072) fp32
    float* __restrict__ hx0,          // [4][3072] ring (k,b), pre-zeroed
    float* __restrict__ hx1,          // [2][3072] parity (k,b), pre-zeroed
    _Float16* __restrict__ h1hist,    // (2048,768) fp16, row = t*4+b
    unsigned* __restrict__ flags)     // [192*32], pre-zeroed
{
  __shared__ __align__(16) float h0buf[H_SZ * 4];  // [k][b]
  __shared__ __align__(16) float h1buf[H_SZ * 4];  // [k][b] (L1 carry)
  __shared__ __align__(16) float red[4][8][4][4];  // [gate][c][q][b]
  __shared__ float actv[4][8][4];                  // [gate][c][b]
  __shared__ float cst[8][4];

  const int t = threadIdx.x, lane = t & 63, wv = t >> 6;
  const bool L1 = blockIdx.x >= 96;
  const int lid = L1 ? (blockIdx.x - 96) : blockIdx.x;
  const int j0 = lid * 8;

  const float* WhhL = Whh + (L1 ? (size_t)G4 * H_SZ : 0);

  // W_hh slice in registers
  float wreg[8][12];
#pragma unroll
  for (int c = 0; c < 8; ++c)
#pragma unroll
    for (int kk = 0; kk < 12; ++kk)
      wreg[c][kk] = WhhL[(size_t)(wv * H_SZ + j0 + c) * H_SZ + kk * 64 + lane];

  // L1 blocks also hold W_ih1 slice
  float wreg2[8][12];
  if (L1) {
#pragma unroll
    for (int c = 0; c < 8; ++c)
#pragma unroll
      for (int kk = 0; kk < 12; ++kk)
        wreg2[c][kk] = Wih1[(size_t)(wv * H_SZ + j0 + c) * H_SZ + kk * 64 + lane];
  }

  const int g_ = t >> 5, c_ = (t >> 2) & 7, b_ = t & 3;

  float breg = 0.f;
  if (L1 && t < 128) breg = bias[G4 + g_ * H_SZ + j0 + c_];

  if (t < 32) cst[t >> 2][t & 3] = 0.f;

  const int elim = L1 ? 513 : 512;
  for (int e = 0; e < elim; ++e) {
    // L0 xg prefetch (independent of h) before the poll
    float xgv = 0.f;
    if (!L1 && t < 128)
      xgv = xg0[(size_t)((e << 2) + b_) * G4 + g_ * H_SZ + j0 + c_];

    if (e >= 1 && t < FUSE_WGS) {
      const unsigned thr = (!L1 && t >= 96) ? (unsigned)(e - 1) : (unsigned)(e + 1);
      while (__hip_atomic_load(&flags[t * 32], __ATOMIC_RELAXED, __HIP_MEMORY_SCOPE_AGENT) < thr)
        __builtin_amdgcn_s_sleep(1);
    }
    __syncthreads();

    // gather h0[e-1] from ring slot (e-1)&3 (e=0 -> slot 3, zeros)
    {
      const ull* s0 = (const ull*)(hx0 + (size_t)(((unsigned)(e - 1)) & 3u) * 3072);
      ull* d0 = (ull*)h0buf;
#pragma unroll
      for (int i = 0; i < 6; ++i)
        d0[t + i * 256] = __hip_atomic_load(&s0[t + i * 256], __ATOMIC_RELAXED, __HIP_MEMORY_SCOPE_AGENT);
      if (L1) {
        const ull* s1 = (const ull*)(hx1 + ((e & 1) ? 3072 : 0));
        ull* d1 = (ull*)h1buf;
#pragma unroll
        for (int i = 0; i < 6; ++i)
          d1[t + i * 256] = __hip_atomic_load(&s1[t + i * 256], __ATOMIC_RELAXED, __HIP_MEMORY_SCOPE_AGENT);
      }
    }
    __syncthreads();

    const bool act = !L1 || (e >= 1);

    if (act) {
      float4 acc[8];
#pragma unroll
      for (int c = 0; c < 8; ++c) acc[c] = make_float4(0.f, 0.f, 0.f, 0.f);

      if (!L1) {
#pragma unroll
        for (int kk = 0; kk < 12; ++kk) {
          float4 h4 = *(const float4*)&h0buf[(kk * 64 + lane) * 4];
#pragma unroll
          for (int c = 0; c < 8; ++c) {
            float wf = wreg[c][kk];
            acc[c].x = fmaf(wf, h4.x, acc[c].x);
            acc[c].y = fmaf(wf, h4.y, acc[c].y);
            acc[c].z = fmaf(wf, h4.z, acc[c].z);
            acc[c].w = fmaf(wf, h4.w, acc[c].w);
          }
        }
      } else {
#pragma unroll
        for (int kk = 0; kk < 12; ++kk) {
          float4 x4 = *(const float4*)&h0buf[(kk * 64 + lane) * 4];  // x = h0[e-1]
          float4 h4 = *(const float4*)&h1buf[(kk * 64 + lane) * 4];  // carry h1[e-2]
#pragma unroll
          for (int c = 0; c < 8; ++c) {
            float wx = wreg2[c][kk], wh = wreg[c][kk];
            acc[c].x = fmaf(wx, x4.x, fmaf(wh, h4.x, acc[c].x));
            acc[c].y = fmaf(wx, x4.y, fmaf(wh, h4.y, acc[c].y));
            acc[c].z = fmaf(wx, x4.z, fmaf(wh, h4.z, acc[c].z));
            acc[c].w = fmaf(wx, x4.w, fmaf(wh, h4.w, acc[c].w));
          }
        }
      }

#pragma unroll
      for (int mask = 1; mask <= 8; mask <<= 1) {
#pragma unroll
        for (int c = 0; c < 8; ++c) {
          acc[c].x += __shfl_xor(acc[c].x, mask, 64);
          acc[c].y += __shfl_xor(acc[c].y, mask, 64);
          acc[c].z += __shfl_xor(acc[c].z, mask, 64);
          acc[c].w += __shfl_xor(acc[c].w, mask, 64);
        }
      }
      if ((lane & 15) == 0) {
        int q = lane >> 4;
#pragma unroll
        for (int c = 0; c < 8; ++c) *(float4*)&red[wv][c][q][0] = acc[c];
      }
    }
    __syncthreads();

    if (act && t < 128) {
      float s = red[g_][c_][0][b_] + red[g_][c_][1][b_] + red[g_][c_][2][b_] + red[g_][c_][3][b_]
              + (L1 ? breg : xgv);
      actv[g_][c_][b_] = (g_ == 2) ? tanhf(s) : (1.f / (1.f + expf(-s)));
    }
    __syncthreads();

    // combine + h-state store (wave 0 lanes 0-31 own ALL state stores)
    float hn_save = 0.f;
    if (act && t < 32) {
      int c = t >> 2, b = t & 3;
      float iv = actv[0][c][b], fv = actv[1][c][b], gv = actv[2][c][b], ov = actv[3][c][b];
      float cn = fv * cst[c][b] + iv * gv;
      cst[c][b] = cn;
      float hn = ov * tanhf(cn);
      hn_save = hn;
      float* hnext = L1 ? (hx1 + (((e + 1) & 1) ? 3072 : 0))
                        : (hx0 + (size_t)(e & 3) * 3072);
      __hip_atomic_store(&hnext[(j0 + c) * 4 + b], hn,
                         __ATOMIC_RELAXED, __HIP_MEMORY_SCOPE_AGENT);
    }

    // publish: drain state stores (wave 0), then flag = e+2
    if (wv == 0) {
      asm volatile("s_waitcnt vmcnt(0)" ::: "memory");
      if (t == 0)
        __hip_atomic_store(&flags[blockIdx.x * 32], (unsigned)(e + 2),
                           __ATOMIC_RELAXED, __HIP_MEMORY_SCOPE_AGENT);
    }

    // deferred h1hist store: off the critical path (no in-kernel consumers)
    if (L1 && act && t < 32) {
      int c = t >> 2, b = t & 3;
      h1hist[(size_t)(((e - 1) << 2) + b) * H_SZ + j0 + c] = (_Float16)hn_save;
    }
    // loop-top poll + __syncthreads separate this epoch's reads from the
    // next epoch's overwrites (ring/parity safety argued in header comment).
  }
}

// ---------------- launcher ----------------

extern "C" void kernel_launch(void* const* d_in, const int* in_sizes, int n_in,
                              void* d_out, int out_size, void* d_ws, size_t ws_size,
                              hipStream_t stream) {
  const float* reps   = (const float*)d_in[0];
  const float* W_ih   = (const float*)d_in[1];
  const float* W_hh   = (const float*)d_in[2];
  const float* bias   = (const float*)d_in[3];
  const float* head_w = (const float*)d_in[4];
  const float* head_b = (const float*)d_in[5];
  float* out = (float*)d_out;

  char* ws = (char*)d_ws;
  _Float16* A0h    = (_Float16*)(ws + 0);            //  3,145,728 B
  _Float16* Wih_h  = (_Float16*)(ws + 3145728);      //  4,718,592 B (layer 0 only)
  _Float16* Whead  = (_Float16*)(ws + 12582912);     // 77,266,944 B (padded)
  float*    xg0    = (float*)   (ws + 89849856);     // 25,165,824 B
  _Float16* h1hist = (_Float16*)(ws + 115015680);    //  3,145,728 B
  float*    hx0    = (float*)   (ws + 118161408);    //     49,152 B ([4][3072] ring)
  float*    hx1    = (float*)   (ws + 118210560);    //     24,576 B ([2][3072])
  unsigned* flags  = (unsigned*)(ws + 118235136);    //     24,576 B (192*128B)

  // conversions
  hipLaunchKernelGGL(conv_A0,   dim3(1024), dim3(256), 0, stream, reps, A0h);
  hipLaunchKernelGGL(conv_cast, dim3(1024), dim3(256), 0, stream, W_ih, Wih_h, G4 * D_SZ);
  hipLaunchKernelGGL(conv_head, dim3(4096), dim3(256), 0, stream, head_w, Whead);

  // xg0 = A0 * Wih0^T + b0
  hipLaunchKernelGGL(gemm_bt_f16, dim3(16, 24), dim3(256), 0, stream,
                     A0h, Wih_h, bias, xg0, M_SZ, G4, H_SZ, 0, G4);

  // decoupled pipelined 2-layer scan (192 blocks x 256 threads, co-resident)
  hipMemsetAsync(hx0, 0, 98304, stream);  // hx0 ring + hx1 + flags contiguous
  hipLaunchKernelGGL(lstm_fused, dim3(FUSE_WGS), dim3(256), 0, stream,
                     xg0, W_ih + (size_t)G4 * D_SZ, W_hh, bias,
                     hx0, hx1, h1hist, flags);

  // logits = h1 * head_w^T + head_b  (padded N, permuted store into (B,T,V))
  hipLaunchKernelGGL(gemm_bt_f16, dim3(16, 393), dim3(256), 0, stream,
                     h1hist, Whead, head_b, out, M_SZ, V_PAD, H_SZ, 1, V_SZ);
}

// Round 12
// 3193.615 us; speedup vs baseline: 3.8383x; 1.2904x over previous
//
#include <hip/hip_runtime.h>
#include <hip/hip_fp16.h>
#include <cstdint>

#define B_SZ 4
#define T_SZ 512
#define D_SZ 768
#define H_SZ 768
#define G4   3072           // 4*H
#define V_SZ 50257
#define V_PAD 50304         // 393*128
#define M_SZ 2048           // T*B
#define FUSE_WGS 192        // 96 L0 blocks + 96 L1 blocks, 256 threads each

using half8 = __attribute__((ext_vector_type(8))) _Float16;
using f32x4 = __attribute__((ext_vector_type(4))) float;
typedef unsigned long long ull;

// ---------------- conversion kernels ----------------

__global__ void conv_A0(const float* __restrict__ reps, _Float16* __restrict__ A0) {
  int idx = blockIdx.x * blockDim.x + threadIdx.x;
  const int total = M_SZ * D_SZ;
  for (; idx < total; idx += gridDim.x * blockDim.x) {
    int k = idx % D_SZ, m = idx / D_SZ;
    int t = m >> 2, b = m & 3;
    A0[idx] = (_Float16)reps[(b * T_SZ + t) * D_SZ + k];
  }
}

__global__ void conv_cast(const float* __restrict__ src, _Float16* __restrict__ dst, int n) {
  int idx = blockIdx.x * blockDim.x + threadIdx.x;
  for (; idx < n; idx += gridDim.x * blockDim.x) dst[idx] = (_Float16)src[idx];
}

__global__ void conv_head(const float* __restrict__ w, _Float16* __restrict__ dst) {
  int idx = blockIdx.x * blockDim.x + threadIdx.x;
  const int total = V_PAD * H_SZ;
  for (; idx < total; idx += gridDim.x * blockDim.x) {
    int n = idx / H_SZ, k = idx % H_SZ;
    dst[idx] = (n < V_SZ) ? (_Float16)w[n * H_SZ + k] : (_Float16)0.f;
  }
}

// ---------------- f16 MFMA GEMM: C[m][n] = sum_k A[m][k]*B[n][k] + bias[n] ----------------

__global__ __launch_bounds__(256) void gemm_bt_f16(
    const _Float16* __restrict__ A, const _Float16* __restrict__ B,
    const float* __restrict__ bias, float* __restrict__ C,
    int M, int N, int K, int mode, int Nreal)
{
  __shared__ __align__(16) _Float16 As[128][32];
  __shared__ __align__(16) _Float16 Bs[128][32];
  const int t = threadIdx.x;
  const int lane = t & 63, w = t >> 6;
  const int wr = w >> 1, wc = w & 1;
  const int m0 = blockIdx.x * 128, n0 = blockIdx.y * 128;

  f32x4 acc[4][4] = {};

  const int srow = t >> 2;
  const int scol = (t & 3) * 8;

  for (int k0 = 0; k0 < K; k0 += 32) {
    uint4 av0 = *(const uint4*)&A[(size_t)(m0 + srow) * K + k0 + scol];
    uint4 av1 = *(const uint4*)&A[(size_t)(m0 + 64 + srow) * K + k0 + scol];
    uint4 bv0 = *(const uint4*)&B[(size_t)(n0 + srow) * K + k0 + scol];
    uint4 bv1 = *(const uint4*)&B[(size_t)(n0 + 64 + srow) * K + k0 + scol];
    __syncthreads();
    *(uint4*)&As[srow][scol]      = av0;
    *(uint4*)&As[64 + srow][scol] = av1;
    *(uint4*)&Bs[srow][scol]      = bv0;
    *(uint4*)&Bs[64 + srow][scol] = bv1;
    __syncthreads();

    const int fr = lane & 15, k8 = (lane >> 4) * 8;
    half8 af[4], bf[4];
#pragma unroll
    for (int i = 0; i < 4; ++i) {
      af[i] = *(const half8*)&As[wr * 64 + i * 16 + fr][k8];
      bf[i] = *(const half8*)&Bs[wc * 64 + i * 16 + fr][k8];
    }
#pragma unroll
    for (int i = 0; i < 4; ++i)
#pragma unroll
      for (int j = 0; j < 4; ++j)
        acc[i][j] = __builtin_amdgcn_mfma_f32_16x16x32_f16(af[i], bf[j], acc[i][j], 0, 0, 0);
  }

  const int fr = lane & 15, rq = lane >> 4;
#pragma unroll
  for (int i = 0; i < 4; ++i) {
#pragma unroll
    for (int j = 0; j < 4; ++j) {
      int n = n0 + wc * 64 + j * 16 + fr;
      if (n >= Nreal) continue;
      float bv = bias[n];
#pragma unroll
      for (int r = 0; r < 4; ++r) {
        int m = m0 + wr * 64 + i * 16 + rq * 4 + r;
        float v = acc[i][j][r] + bv;
        if (mode == 0) {
          C[(size_t)m * N + n] = v;
        } else {
          int tt = m >> 2, bb = m & 3;
          C[(size_t)(bb * T_SZ + tt) * V_SZ + n] = v;
        }
      }
    }
  }
}

// ---------------- tag-synchronized 2-group pipelined LSTM scan ----------------
// 192 blocks x 256 threads: blocks 0..95 = L0, 96..191 = L1 (lag-1 pipeline).
// THE ROUND-12 CHANGE: h state words are [tag:u32 | f32-bits:u32] packed in
// one aligned 8B word, stored/loaded with single relaxed agent-scope 8B
// atomics (single-copy atomic => tag travels WITH data). The reader's tag
// poll IS the gather: no separate flag hop, no vmcnt drain on the critical
// path. Tag stored at epoch e = e+1; reader at epoch x expects tag x.
//   h0: depth-4 ring hx0p[4][3072]; slot s holds h0[s mod-4 sequence].
//   h1: parity pair hx1p[2][3072].
// Forward safety: transitive through tags (tag e on all slots => all peers
// finished epoch e-1 => finished all reads of epochs <= e-2).
// Anti-dependence (overwrite) guards still need flags (a reader lapped by a
// writer would accept tag > expected since poll is "< expected"):
//   L0 before storing slot e&3 (kills h0[e-4], last read by L1 at its epoch
//   e-3): L1 flags >= e-1.   L1 before storing parity (e+1)&1 (kills
//   h1[e-3], last read by L1 peers at epoch e-1): own L1 flags >= e+1.
// Both checks run during the activation phase (threads 128..223) and are
// pre-satisfied in steady state. Flag = e+2 published at epoch end.
// L1 seeds parity-1 with (0.0f, tag 1) at e=0 so epoch-1 readers proceed.
// All tags/flags memset 0 per launch: deterministic graph replay.

__global__ __launch_bounds__(256) void lstm_fused(
    const float* __restrict__ xg0,    // (2048,3072) layer-0 input projections
    const float* __restrict__ Wih1,   // (3072,768) fp32 layer-1 input weights
    const float* __restrict__ Whh,    // (2,3072,768) fp32
    const float* __restrict__ bias,   // (2,3072) fp32
    ull* __restrict__ hx0p,           // [4][3072] packed ring, pre-zeroed
    ull* __restrict__ hx1p,           // [2][3072] packed parity, pre-zeroed
    _Float16* __restrict__ h1hist,    // (2048,768) fp16, row = t*4+b
    unsigned* __restrict__ flags)     // [192*32], pre-zeroed
{
  __shared__ __align__(16) float h0buf[H_SZ * 4];  // [k][b]
  __shared__ __align__(16) float h1buf[H_SZ * 4];  // [k][b] (L1 carry)
  __shared__ __align__(16) float red[4][8][4][4];  // [gate][c][q][b]
  __shared__ float actv[4][8][4];                  // [gate][c][b]
  __shared__ float cst[8][4];

  const int t = threadIdx.x, lane = t & 63, wv = t >> 6;
  const bool L1 = blockIdx.x >= 96;
  const int lid = L1 ? (blockIdx.x - 96) : blockIdx.x;
  const int j0 = lid * 8;

  const float* WhhL = Whh + (L1 ? (size_t)G4 * H_SZ : 0);

  // W_hh slice in registers
  float wreg[8][12];
#pragma unroll
  for (int c = 0; c < 8; ++c)
#pragma unroll
    for (int kk = 0; kk < 12; ++kk)
      wreg[c][kk] = WhhL[(size_t)(wv * H_SZ + j0 + c) * H_SZ + kk * 64 + lane];

  // L1 blocks also hold W_ih1 slice
  float wreg2[8][12];
  if (L1) {
#pragma unroll
    for (int c = 0; c < 8; ++c)
#pragma unroll
      for (int kk = 0; kk < 12; ++kk)
        wreg2[c][kk] = Wih1[(size_t)(wv * H_SZ + j0 + c) * H_SZ + kk * 64 + lane];
  }

  const int g_ = t >> 5, c_ = (t >> 2) & 7, b_ = t & 3;

  float breg = 0.f;
  if (L1 && t < 128) breg = bias[G4 + g_ * H_SZ + j0 + c_];

  if (t < 32) cst[t >> 2][t & 3] = 0.f;

  const int elim = L1 ? 513 : 512;
  for (int e = 0; e < elim; ++e) {
    // L0 xg prefetch (independent of h) before the tag poll
    float xgv = 0.f;
    if (!L1 && t < 128)
      xgv = xg0[(size_t)((e << 2) + b_) * G4 + g_ * H_SZ + j0 + c_];

    const unsigned need = (unsigned)e;

    // ---- tag-gated gather h0[e-1] from ring slot (e-1)&3 ----
    {
      const ull* s0 = hx0p + (size_t)(((unsigned)(e + 3)) & 3u) * 3072;
      ull v[12];
#pragma unroll
      for (int i = 0; i < 12; ++i)
        v[i] = __hip_atomic_load(&s0[t + i * 256], __ATOMIC_RELAXED, __HIP_MEMORY_SCOPE_AGENT);
      for (;;) {
        bool stale = false;
#pragma unroll
        for (int i = 0; i < 12; ++i) stale |= ((unsigned)(v[i] >> 32) < need);
        if (!stale) break;
        __builtin_amdgcn_s_sleep(1);
#pragma unroll
        for (int i = 0; i < 12; ++i)
          if ((unsigned)(v[i] >> 32) < need)
            v[i] = __hip_atomic_load(&s0[t + i * 256], __ATOMIC_RELAXED, __HIP_MEMORY_SCOPE_AGENT);
      }
#pragma unroll
      for (int i = 0; i < 12; ++i) h0buf[t + i * 256] = __uint_as_float((unsigned)v[i]);
    }
    // ---- L1: tag-gated gather h1[e-2] from parity e&1 ----
    if (L1) {
      const ull* s1 = hx1p + (size_t)(e & 1) * 3072;
      ull v[12];
#pragma unroll
      for (int i = 0; i < 12; ++i)
        v[i] = __hip_atomic_load(&s1[t + i * 256], __ATOMIC_RELAXED, __HIP_MEMORY_SCOPE_AGENT);
      for (;;) {
        bool stale = false;
#pragma unroll
        for (int i = 0; i < 12; ++i) stale |= ((unsigned)(v[i] >> 32) < need);
        if (!stale) break;
        __builtin_amdgcn_s_sleep(1);
#pragma unroll
        for (int i = 0; i < 12; ++i)
          if ((unsigned)(v[i] >> 32) < need)
            v[i] = __hip_atomic_load(&s1[t + i * 256], __ATOMIC_RELAXED, __HIP_MEMORY_SCOPE_AGENT);
      }
#pragma unroll
      for (int i = 0; i < 12; ++i) h1buf[t + i * 256] = __uint_as_float((unsigned)v[i]);
    }
    __syncthreads();

    const bool act = !L1 || (e >= 1);

    if (act) {
      float4 acc[8];
#pragma unroll
      for (int c = 0; c < 8; ++c) acc[c] = make_float4(0.f, 0.f, 0.f, 0.f);

      if (!L1) {
#pragma unroll
        for (int kk = 0; kk < 12; ++kk) {
          float4 h4 = *(const float4*)&h0buf[(kk * 64 + lane) * 4];
#pragma unroll
          for (int c = 0; c < 8; ++c) {
            float wf = wreg[c][kk];
            acc[c].x = fmaf(wf, h4.x, acc[c].x);
            acc[c].y = fmaf(wf, h4.y, acc[c].y);
            acc[c].z = fmaf(wf, h4.z, acc[c].z);
            acc[c].w = fmaf(wf, h4.w, acc[c].w);
          }
        }
      } else {
#pragma unroll
        for (int kk = 0; kk < 12; ++kk) {
          float4 x4 = *(const float4*)&h0buf[(kk * 64 + lane) * 4];  // x = h0[e-1]
          float4 h4 = *(const float4*)&h1buf[(kk * 64 + lane) * 4];  // carry h1[e-2]
#pragma unroll
          for (int c = 0; c < 8; ++c) {
            float wx = wreg2[c][kk], wh = wreg[c][kk];
            acc[c].x = fmaf(wx, x4.x, fmaf(wh, h4.x, acc[c].x));
            acc[c].y = fmaf(wx, x4.y, fmaf(wh, h4.y, acc[c].y));
            acc[c].z = fmaf(wx, x4.z, fmaf(wh, h4.z, acc[c].z));
            acc[c].w = fmaf(wx, x4.w, fmaf(wh, h4.w, acc[c].w));
          }
        }
      }

#pragma unroll
      for (int mask = 1; mask <= 8; mask <<= 1) {
#pragma unroll
        for (int c = 0; c < 8; ++c) {
          acc[c].x += __shfl_xor(acc[c].x, mask, 64);
          acc[c].y += __shfl_xor(acc[c].y, mask, 64);
          acc[c].z += __shfl_xor(acc[c].z, mask, 64);
          acc[c].w += __shfl_xor(acc[c].w, mask, 64);
        }
      }
      if ((lane & 15) == 0) {
        int q = lane >> 4;
#pragma unroll
        for (int c = 0; c < 8; ++c) *(float4*)&red[wv][c][q][0] = acc[c];
      }
    }
    __syncthreads();

    // activation phase (t<128) + anti-dependence flag check (t in [128,224))
    if (act && t < 128) {
      float s = red[g_][c_][0][b_] + red[g_][c_][1][b_] + red[g_][c_][2][b_] + red[g_][c_][3][b_]
              + (L1 ? breg : xgv);
      actv[g_][c_][b_] = (g_ == 2) ? tanhf(s) : (1.f / (1.f + expf(-s)));
    } else if (e >= 1 && t >= 128 && t < 128 + 96) {
      const int idx = 96 + (t - 128);               // L1-group flag line
      const unsigned thr = L1 ? (unsigned)(e + 1) : (unsigned)(e - 1);
      while (__hip_atomic_load(&flags[idx * 32], __ATOMIC_RELAXED, __HIP_MEMORY_SCOPE_AGENT) < thr)
        __builtin_amdgcn_s_sleep(1);
    }
    __syncthreads();

    // combine + packed h store (wave 0 lanes 0-31), or L1 epoch-0 seed
    float hn_save = 0.f;
    if (t < 32) {
      if (act) {
        int c = t >> 2, b = t & 3;
        float iv = actv[0][c][b], fv = actv[1][c][b], gv = actv[2][c][b], ov = actv[3][c][b];
        float cn = fv * cst[c][b] + iv * gv;
        cst[c][b] = cn;
        float hn = ov * tanhf(cn);
        hn_save = hn;
        ull p = ((ull)(unsigned)(e + 1) << 32) | (ull)__float_as_uint(hn);
        ull* dst = L1 ? (hx1p + (size_t)((e + 1) & 1) * 3072)
                      : (hx0p + (size_t)(e & 3) * 3072);
        __hip_atomic_store(&dst[(j0 + c) * 4 + b], p,
                           __ATOMIC_RELAXED, __HIP_MEMORY_SCOPE_AGENT);
      } else if (L1) {
        // e == 0: seed h1 parity-1 with zeros, tag 1 (h1[-1])
        int c = t >> 2, b = t & 3;
        ull p = ((ull)1u << 32);
        __hip_atomic_store(&hx1p[3072 + (j0 + c) * 4 + b], p,
                           __ATOMIC_RELAXED, __HIP_MEMORY_SCOPE_AGENT);
      }
    }

    // flag publish (anti-dep bookkeeping only; off the forward critical path)
    if (wv == 0) {
      asm volatile("s_waitcnt vmcnt(0)" ::: "memory");
      if (t == 0)
        __hip_atomic_store(&flags[blockIdx.x * 32], (unsigned)(e + 2),
                           __ATOMIC_RELAXED, __HIP_MEMORY_SCOPE_AGENT);
    }

    // deferred h1hist store (no in-kernel consumers)
    if (L1 && act && t < 32) {
      int c = t >> 2, b = t & 3;
      h1hist[(size_t)(((e - 1) << 2) + b) * H_SZ + j0 + c] = (_Float16)hn_save;
    }
  }
}

// ---------------- launcher ----------------

extern "C" void kernel_launch(void* const* d_in, const int* in_sizes, int n_in,
                              void* d_out, int out_size, void* d_ws, size_t ws_size,
                              hipStream_t stream) {
  const float* reps   = (const float*)d_in[0];
  const float* W_ih   = (const float*)d_in[1];
  const float* W_hh   = (const float*)d_in[2];
  const float* bias   = (const float*)d_in[3];
  const float* head_w = (const float*)d_in[4];
  const float* head_b = (const float*)d_in[5];
  float* out = (float*)d_out;

  char* ws = (char*)d_ws;
  _Float16* A0h    = (_Float16*)(ws + 0);            //  3,145,728 B
  _Float16* Wih_h  = (_Float16*)(ws + 3145728);      //  4,718,592 B (layer 0 only)
  _Float16* Whead  = (_Float16*)(ws + 12582912);     // 77,266,944 B (padded)
  float*    xg0    = (float*)   (ws + 89849856);     // 25,165,824 B
  _Float16* h1hist = (_Float16*)(ws + 115015680);    //  3,145,728 B
  ull*      hx0p   = (ull*)     (ws + 118161408);    //     98,304 B ([4][3072] packed)
  ull*      hx1p   = (ull*)     (ws + 118259712);    //     49,152 B ([2][3072] packed)
  unsigned* flags  = (unsigned*)(ws + 118308864);    //     24,576 B (192*128B)

  // conversions
  hipLaunchKernelGGL(conv_A0,   dim3(1024), dim3(256), 0, stream, reps, A0h);
  hipLaunchKernelGGL(conv_cast, dim3(1024), dim3(256), 0, stream, W_ih, Wih_h, G4 * D_SZ);
  hipLaunchKernelGGL(conv_head, dim3(4096), dim3(256), 0, stream, head_w, Whead);

  // xg0 = A0 * Wih0^T + b0
  hipLaunchKernelGGL(gemm_bt_f16, dim3(16, 24), dim3(256), 0, stream,
                     A0h, Wih_h, bias, xg0, M_SZ, G4, H_SZ, 0, G4);

  // tag-synchronized pipelined 2-layer scan (192 blocks x 256 threads)
  hipMemsetAsync(hx0p, 0, 172032, stream);  // hx0p + hx1p + flags contiguous
  hipLaunchKernelGGL(lstm_fused, dim3(FUSE_WGS), dim3(256), 0, stream,
                     xg0, W_ih + (size_t)G4 * D_SZ, W_hh, bias,
                     hx0p, hx1p, h1hist, flags);

  // logits = h1 * head_w^T + head_b  (padded N, permuted store into (B,T,V))
  hipLaunchKernelGGL(gemm_bt_f16, dim3(16, 393), dim3(256), 0, stream,
                     h1hist, Whead, head_b, out, M_SZ, V_PAD, H_SZ, 1, V_SZ);
}